// Round 1
// baseline (365.677 us; speedup 1.0000x reference)
//
#include <hip/hip_runtime.h>

#define BB 8
#define CC 256
#define HH 96
#define WW 96
#define HWW (HH*WW)
#define PLOC 256        // local prototypes
#define PPAD 257        // + global prototype
#define KH 6
#define KW 6
#define THRESH 0.95f
#define NORM_EPS 1e-4f

// ---------------- kernel 0: pooled masks -> valid flags + mask sum ----------
__global__ void k0_masks(const float* __restrict__ sup_mask,
                         const float* __restrict__ true_bg,
                         float* __restrict__ validf,
                         float* __restrict__ masksum) {
    int b = blockIdx.x;
    int t = threadIdx.x;            // cell index 0..255
    int gy = t >> 4, gx = t & 15;
    const float* mb = sup_mask + (size_t)b * HWW;
    const float* gb = true_bg  + (size_t)b * HWW;
    int base = gy * KH * WW + gx * KW;
    float ms = 0.f, bs = 0.f;
    for (int r = 0; r < KH; ++r)
        for (int j = 0; j < KW; ++j) {
            ms += mb[base + r * WW + j];
            bs += gb[base + r * WW + j];
        }
    float mmean = ms * (1.f / 36.f);
    float bmean = bs * (1.f / 36.f);
    validf[b * PPAD + t] = (mmean > THRESH && bmean < 0.5f) ? 1.f : 0.f;
    if (t == 0) validf[b * PPAD + 256] = 1.f;   // global proto always valid

    __shared__ float red[256];
    red[t] = ms;
    __syncthreads();
    for (int off = 128; off > 0; off >>= 1) {
        if (t < off) red[t] += red[t + off];
        __syncthreads();
    }
    if (t == 0) masksum[b] = red[0];
}

// ---------------- kernel 1: avg-pool sup_fts + masked sums (gproto numer) ---
__global__ void k1_pool(const float* __restrict__ sup_fts,
                        const float* __restrict__ sup_mask,
                        float* __restrict__ protos) {
    int bc = blockIdx.x;
    int b = bc >> 8;
    int c = bc & 255;
    int t = threadIdx.x;            // cell index
    int gy = t >> 4, gx = t & 15;
    const float* fb = sup_fts + ((size_t)b * CC + c) * HWW;
    const float* mb = sup_mask + (size_t)b * HWW;
    int base = gy * KH * WW + gx * KW;
    float fs = 0.f, fm = 0.f;
    for (int r = 0; r < KH; ++r)
        for (int j = 0; j < KW; ++j) {
            float v = fb[base + r * WW + j];
            float mk = mb[base + r * WW + j];
            fs += v;
            fm = fmaf(v, mk, fm);
        }
    protos[((size_t)b * PPAD + t) * CC + c] = fs * (1.f / 36.f);

    __shared__ float red[256];
    red[t] = fm;
    __syncthreads();
    for (int off = 128; off > 0; off >>= 1) {
        if (t < off) red[t] += red[t + off];
        __syncthreads();
    }
    if (t == 0) protos[((size_t)b * PPAD + 256) * CC + c] = red[0]; // gproto numerator
}

// ---------------- kernel 2: finish gproto + L2-normalize all protos ---------
__global__ void k2_norm(float* __restrict__ protos,
                        const float* __restrict__ masksum) {
    int bp = blockIdx.x;
    int b = bp / PPAD;
    int p = bp - b * PPAD;
    int t = threadIdx.x;            // channel
    float v = protos[((size_t)b * PPAD + p) * CC + t];
    if (p == 256) v = v / (masksum[b] + 1e-5f);
    __shared__ float red[256];
    red[t] = v * v;
    __syncthreads();
    for (int off = 128; off > 0; off >>= 1) {
        if (t < off) red[t] += red[t + off];
        __syncthreads();
    }
    float norm = sqrtf(red[0]);
    float r = 1.f / fmaxf(norm, NORM_EPS);
    protos[((size_t)b * PPAD + p) * CC + t] = v * r;
}

// ---------------- kernel 3: dists + masked online softmax + weighted sum ----
// block = 256 threads = 4 waves; 64 pixels per block (lane = pixel);
// wave w handles protos [w*64, w*64+64); wave 0 also handles the global proto.
__global__ __launch_bounds__(256, 4)
void k3_main(const float* __restrict__ qry,
             const float* __restrict__ protos,
             const float* __restrict__ validf,
             float* __restrict__ out) {
    int bid = blockIdx.x;
    int b = bid / (HWW / 64);
    int tile = bid - b * (HWW / 64);
    int lane = threadIdx.x & 63;
    int wv = __builtin_amdgcn_readfirstlane((int)(threadIdx.x >> 6)); // wave-uniform
    int px = tile * 64 + lane;

    const float* qb = qry + (size_t)b * CC * HWW + px;
    const float* pgbase = protos + ((size_t)b * PPAD + wv * 64) * CC;
    const float* gp = protos + ((size_t)b * PPAD + 256) * CC;
    const float* vb = validf + b * PPAD + wv * 64;

    float acc[64];
#pragma unroll
    for (int p = 0; p < 64; ++p) acc[p] = 0.f;
    float accg = 0.f, norm2 = 0.f;

    for (int cc = 0; cc < CC; cc += 32) {
        float q[32];
#pragma unroll
        for (int j = 0; j < 32; ++j) q[j] = qb[(size_t)(cc + j) * HWW];
#pragma unroll
        for (int j = 0; j < 32; ++j) norm2 = fmaf(q[j], q[j], norm2);
        if (wv == 0) {
#pragma unroll
            for (int j = 0; j < 32; ++j) accg = fmaf(q[j], gp[cc + j], accg);
        }
#pragma unroll
        for (int p = 0; p < 64; ++p) {
            const float* pp = pgbase + p * CC + cc;
#pragma unroll
            for (int j = 0; j < 32; ++j) acc[p] = fmaf(q[j], pp[j], acc[p]);
        }
    }

    float rnorm = 1.f / fmaxf(sqrtf(norm2), NORM_EPS);

    // online softmax over this wave's protos
    float m = -1e30f, s = 0.f, n = 0.f;
    if (wv == 0) {
        float dg = accg * rnorm;
        m = dg; s = 1.f; n = dg;
    }
#pragma unroll
    for (int p = 0; p < 64; ++p) {
        float d = acc[p] * rnorm;
        float l = (vb[p] != 0.f) ? d : -1e30f;
        float m2 = fmaxf(m, l);
        float sc = __expf(m - m2);
        float e  = __expf(l - m2);
        s = fmaf(s, sc, e);
        n = fmaf(n, sc, e * l);
        m = m2;
    }

    // merge the 4 waves' online states per pixel
    __shared__ float lsm[4][64], lss[4][64], lsn[4][64];
    lsm[wv][lane] = m; lss[wv][lane] = s; lsn[wv][lane] = n;
    __syncthreads();
    if (threadIdx.x < 64) {
        int t = threadIdx.x;
        float m0 = lsm[0][t], m1 = lsm[1][t], m2 = lsm[2][t], m3 = lsm[3][t];
        float mm = fmaxf(fmaxf(m0, m1), fmaxf(m2, m3));
        float a0 = __expf(m0 - mm), a1 = __expf(m1 - mm);
        float a2 = __expf(m2 - mm), a3 = __expf(m3 - mm);
        float S = lss[0][t] * a0 + lss[1][t] * a1 + lss[2][t] * a2 + lss[3][t] * a3;
        float N = lsn[0][t] * a0 + lsn[1][t] * a1 + lsn[2][t] * a2 + lsn[3][t] * a3;
        out[(size_t)b * HWW + tile * 64 + t] = N / S;
    }
}

extern "C" void kernel_launch(void* const* d_in, const int* in_sizes, int n_in,
                              void* d_out, int out_size, void* d_ws, size_t ws_size,
                              hipStream_t stream) {
    const float* qry = (const float*)d_in[0];
    const float* sup = (const float*)d_in[1];
    const float* msk = (const float*)d_in[2];
    const float* bg  = (const float*)d_in[3];
    float* out = (float*)d_out;

    float* ws = (float*)d_ws;
    float* protos  = ws;                                  // [B][257][256]
    float* validf  = protos + (size_t)BB * PPAD * CC;     // [B][257]
    float* masksum = validf + (size_t)BB * PPAD;          // [B]

    hipLaunchKernelGGL(k0_masks, dim3(BB), dim3(256), 0, stream, msk, bg, validf, masksum);
    hipLaunchKernelGGL(k1_pool, dim3(BB * CC), dim3(256), 0, stream, sup, msk, protos);
    hipLaunchKernelGGL(k2_norm, dim3(BB * PPAD), dim3(256), 0, stream, protos, masksum);
    hipLaunchKernelGGL(k3_main, dim3(BB * (HWW / 64)), dim3(256), 0, stream,
                       qry, protos, validf, out);
}

// Round 3
// 80.529 us; speedup vs baseline: 4.5409x; 4.5409x over previous
//
#include <hip/hip_runtime.h>

#define BB 8
#define CC 256
#define HH 96
#define WW 96
#define HWW (HH*WW)
#define NLOC 256        // local prototypes (MFMA path)
#define PPAD 257        // + global prototype
#define KH 6
#define KW 6
#define THRESH 0.95f
#define NORM_EPS 1e-4f

typedef __attribute__((ext_vector_type(8))) short bf16x8;
typedef __attribute__((ext_vector_type(4))) float f32x4;

// ---------------- kernel 0: pooled masks -> valid flags + mask sum ----------
__global__ void k0_masks(const float* __restrict__ sup_mask,
                         const float* __restrict__ true_bg,
                         float* __restrict__ validf,
                         float* __restrict__ masksum) {
    int b = blockIdx.x;
    int t = threadIdx.x;            // cell index 0..255
    int gy = t >> 4, gx = t & 15;
    const float* mb = sup_mask + (size_t)b * HWW;
    const float* gb = true_bg  + (size_t)b * HWW;
    int base = gy * KH * WW + gx * KW;
    float ms = 0.f, bs = 0.f;
    for (int r = 0; r < KH; ++r)
        for (int j = 0; j < KW; ++j) {
            ms += mb[base + r * WW + j];
            bs += gb[base + r * WW + j];
        }
    float mmean = ms * (1.f / 36.f);
    float bmean = bs * (1.f / 36.f);
    validf[b * PPAD + t] = (mmean > THRESH && bmean < 0.5f) ? 1.f : 0.f;
    if (t == 0) validf[b * PPAD + 256] = 1.f;

    __shared__ float red[256];
    red[t] = ms;
    __syncthreads();
    for (int off = 128; off > 0; off >>= 1) {
        if (t < off) red[t] += red[t + off];
        __syncthreads();
    }
    if (t == 0) masksum[b] = red[0];
}

// ---------------- kernel 1: avg-pool sup_fts + masked sums (gproto numer) ---
__global__ void k1_pool(const float* __restrict__ sup_fts,
                        const float* __restrict__ sup_mask,
                        float* __restrict__ protos) {
    int bc = blockIdx.x;
    int b = bc >> 8;
    int c = bc & 255;
    int t = threadIdx.x;            // cell index
    int gy = t >> 4, gx = t & 15;
    const float* fb = sup_fts + ((size_t)b * CC + c) * HWW;
    const float* mb = sup_mask + (size_t)b * HWW;
    int base = gy * KH * WW + gx * KW;
    float fs = 0.f, fm = 0.f;
    for (int r = 0; r < KH; ++r)
        for (int j = 0; j < KW; ++j) {
            float v = fb[base + r * WW + j];
            float mk = mb[base + r * WW + j];
            fs += v;
            fm = fmaf(v, mk, fm);
        }
    protos[((size_t)b * PPAD + t) * CC + c] = fs * (1.f / 36.f);

    __shared__ float red[256];
    red[t] = fm;
    __syncthreads();
    for (int off = 128; off > 0; off >>= 1) {
        if (t < off) red[t] += red[t + off];
        __syncthreads();
    }
    if (t == 0) protos[((size_t)b * PPAD + 256) * CC + c] = red[0];
}

// ------- kernel 2: finish gproto + normalize + emit bf16 hi/lo B-image ------
// Bimg layout (halves): [B][8 kc][2 hi/lo][256 p][40]  (rows padded 32->40)
__global__ void k2_norm(float* __restrict__ protos,
                        const float* __restrict__ masksum,
                        unsigned short* __restrict__ Bimg) {
    int bp = blockIdx.x;
    int b = bp / PPAD;
    int p = bp - b * PPAD;
    int t = threadIdx.x;            // channel
    float v = protos[((size_t)b * PPAD + p) * CC + t];
    if (p == 256) v = v / (masksum[b] + 1e-5f);
    __shared__ float red[256];
    red[t] = v * v;
    __syncthreads();
    for (int off = 128; off > 0; off >>= 1) {
        if (t < off) red[t] += red[t + off];
        __syncthreads();
    }
    float norm = sqrtf(red[0]);
    float vn = v / fmaxf(norm, NORM_EPS);
    protos[((size_t)b * PPAD + p) * CC + t] = vn;
    if (p < NLOC) {
        unsigned int u = __float_as_uint(vn);
        unsigned short hi = (unsigned short)(u >> 16);          // truncation
        float lo = vn - __uint_as_float(u & 0xffff0000u);       // exact
        unsigned int ul = __float_as_uint(lo);
        unsigned short lob = (unsigned short)((ul + 0x7fffu + ((ul >> 16) & 1u)) >> 16); // RNE
        int kc = t >> 5, j = t & 31;
        size_t base = (((size_t)b * 8 + kc) * 2) * (NLOC * 40);
        Bimg[base + (size_t)p * 40 + j] = hi;
        Bimg[base + (size_t)(NLOC * 40) + (size_t)p * 40 + j] = lob;
    }
}

// ---------------- kernel 3: MFMA dists + masked softmax + weighted sum ------
// block = 256 thr = 4 waves; wave w owns 32 pixels (2 subtiles of 16), N=256.
__global__ __launch_bounds__(256, 2)
void k3_mfma(const float* __restrict__ qry,
             const unsigned short* __restrict__ Bimg,
             const float* __restrict__ protos_n,
             const float* __restrict__ validf,
             float* __restrict__ out) {
    __shared__ alignas(16) unsigned short Blds[2 * NLOC * 40];   // 40960 B

    int bid = blockIdx.x;
    int b = bid / (HWW / 128);
    int tile = bid - b * (HWW / 128);
    int t = threadIdx.x;
    int lane = t & 63;
    int w = t >> 6;
    int g = lane >> 4;        // k-group within wave
    int n = lane & 15;        // col lane (proto) / pixel lane for loads
    int px0 = tile * 128 + w * 32;

    const float* qb = qry + (size_t)b * CC * HWW;
    const float* gp = protos_n + ((size_t)b * PPAD + 256) * CC;
    const unsigned short* Bg = Bimg + (size_t)b * 8 * 2 * (NLOC * 40);
    const char* ldsb_c = (const char*)Blds;

    f32x4 acc[2][16];
#pragma unroll
    for (int sub = 0; sub < 2; ++sub)
#pragma unroll
        for (int tt = 0; tt < 16; ++tt)
            acc[sub][tt] = (f32x4){0.f, 0.f, 0.f, 0.f};
    float norm2[2] = {0.f, 0.f};
    float gacc[2] = {0.f, 0.f};

    for (int kc = 0; kc < 8; ++kc) {
        // ---- stage B k-chunk (40960 B) global -> LDS ----
        const char* src = (const char*)(Bg + (size_t)kc * 2 * (NLOC * 40));
        {
            int goff = t * 16;                       // per-lane global offset
            int loff = (t >> 6) * 1024;              // wave-uniform LDS base
#pragma unroll
            for (int i = 0; i < 10; ++i) {
                __builtin_amdgcn_global_load_lds(
                    (const void*)(src + i * 4096 + goff),
                    (void*)(ldsb_c + i * 4096 + loff),
                    16, 0, 0);
            }
        }
        __syncthreads();

        int c0 = kc * 32;
        // ---- gproto slice (shared by both subtiles) ----
        float gpv[8];
#pragma unroll
        for (int j = 0; j < 8; ++j) gpv[j] = gp[c0 + 8 * g + j];

        // ---- A: load fp32 q, split to bf16 hi/lo in-register ----
        bf16x8 ah[2], al[2];
#pragma unroll
        for (int sub = 0; sub < 2; ++sub) {
            int px = px0 + sub * 16 + n;
            const float* qcol = qb + (size_t)(c0 + 8 * g) * HWW + px;
            float q[8];
#pragma unroll
            for (int j = 0; j < 8; ++j) q[j] = qcol[(size_t)j * HWW];
            union { bf16x8 v; unsigned int u[4]; } H, L;
#pragma unroll
            for (int jp = 0; jp < 4; ++jp) {
                unsigned int u0 = __float_as_uint(q[2 * jp]);
                unsigned int u1 = __float_as_uint(q[2 * jp + 1]);
                H.u[jp] = (u0 >> 16) | (u1 & 0xffff0000u);
                float lo0 = q[2 * jp]     - __uint_as_float(u0 & 0xffff0000u);
                float lo1 = q[2 * jp + 1] - __uint_as_float(u1 & 0xffff0000u);
                unsigned int r0 = __float_as_uint(lo0);
                unsigned int r1 = __float_as_uint(lo1);
                r0 = (r0 + 0x7fffu + ((r0 >> 16) & 1u)) >> 16;
                r1 = (r1 + 0x7fffu + ((r1 >> 16) & 1u)) & 0xffff0000u;
                L.u[jp] = r0 | r1;
            }
            ah[sub] = H.v; al[sub] = L.v;
#pragma unroll
            for (int j = 0; j < 8; ++j) norm2[sub] = fmaf(q[j], q[j], norm2[sub]);
#pragma unroll
            for (int j = 0; j < 8; ++j) gacc[sub] = fmaf(q[j], gpv[j], gacc[sub]);
        }

        // ---- B frags from LDS + MFMA ----
#pragma unroll
        for (int tt = 0; tt < 16; ++tt) {
            int rowoff = (tt * 16 + n) * 40 + g * 8;       // halves
            bf16x8 bh = *(const bf16x8*)&Blds[rowoff];
            bf16x8 bl = *(const bf16x8*)&Blds[NLOC * 40 + rowoff];
#pragma unroll
            for (int sub = 0; sub < 2; ++sub) {
                acc[sub][tt] = __builtin_amdgcn_mfma_f32_16x16x32_bf16(ah[sub], bh, acc[sub][tt], 0, 0, 0);
                acc[sub][tt] = __builtin_amdgcn_mfma_f32_16x16x32_bf16(al[sub], bh, acc[sub][tt], 0, 0, 0);
                acc[sub][tt] = __builtin_amdgcn_mfma_f32_16x16x32_bf16(ah[sub], bl, acc[sub][tt], 0, 0, 0);
            }
        }
        __syncthreads();
    }

    // ---- reduce |q|^2 and g-dot over k-groups (lanes n, n+16, n+32, n+48) --
#pragma unroll
    for (int sub = 0; sub < 2; ++sub) {
        norm2[sub] += __shfl_xor(norm2[sub], 16);
        norm2[sub] += __shfl_xor(norm2[sub], 32);
        gacc[sub]  += __shfl_xor(gacc[sub], 16);
        gacc[sub]  += __shfl_xor(gacc[sub], 32);
    }

    // per-row (px = px0 + sub*16 + 4g + r) norm & global-proto dist
    float rnorm[2][4], gd[2][4];
#pragma unroll
    for (int sub = 0; sub < 2; ++sub)
#pragma unroll
        for (int r = 0; r < 4; ++r) {
            float n2 = __shfl(norm2[sub], 4 * g + r);
            float rn = 1.f / fmaxf(sqrtf(n2), NORM_EPS);
            rnorm[sub][r] = rn;
            gd[sub][r] = __shfl(gacc[sub], 4 * g + r) * rn;
        }

    // valid flags for this lane's proto column across the 16 tiles
    float vf[16];
    const float* vb = validf + b * PPAD;
#pragma unroll
    for (int tt = 0; tt < 16; ++tt) vf[tt] = vb[tt * 16 + n];

    // ---- softmax (fixed shift 1.1, cosines bounded) + weighted sum ----
    // NOTE: global-proto term added ONCE per pixel AFTER the 16-lane
    // reduction (seeding it per-lane would count it 16x — round-2 bug).
#pragma unroll
    for (int sub = 0; sub < 2; ++sub) {
        float S[4] = {0.f, 0.f, 0.f, 0.f};
        float NN[4] = {0.f, 0.f, 0.f, 0.f};
#pragma unroll
        for (int tt = 0; tt < 16; ++tt) {
#pragma unroll
            for (int r = 0; r < 4; ++r) {
                float d = acc[sub][tt][r] * rnorm[sub][r];
                float l = (vf[tt] != 0.f) ? d : -1e30f;
                float e = __expf(l - 1.1f);          // underflows to exactly 0 when masked
                S[r] += e;
                NN[r] = fmaf(e, l, NN[r]);
            }
        }
#pragma unroll
        for (int r = 0; r < 4; ++r) {
#pragma unroll
            for (int m = 1; m < 16; m <<= 1) {
                S[r]  += __shfl_xor(S[r], m);
                NN[r] += __shfl_xor(NN[r], m);
            }
            float eg = __expf(gd[sub][r] - 1.1f);    // global proto, exactly once
            S[r] += eg;
            NN[r] = fmaf(eg, gd[sub][r], NN[r]);
        }
        if (n < 4) {   // lane (g, n<4) writes row 4g+n, slot r=n
            float Ssel = (n == 0) ? S[0] : (n == 1) ? S[1] : (n == 2) ? S[2] : S[3];
            float Nsel = (n == 0) ? NN[0] : (n == 1) ? NN[1] : (n == 2) ? NN[2] : NN[3];
            out[(size_t)b * HWW + px0 + sub * 16 + 4 * g + n] = Nsel / Ssel;
        }
    }
}

extern "C" void kernel_launch(void* const* d_in, const int* in_sizes, int n_in,
                              void* d_out, int out_size, void* d_ws, size_t ws_size,
                              hipStream_t stream) {
    const float* qry = (const float*)d_in[0];
    const float* sup = (const float*)d_in[1];
    const float* msk = (const float*)d_in[2];
    const float* bg  = (const float*)d_in[3];
    float* out = (float*)d_out;

    float* ws = (float*)d_ws;
    float* protos  = ws;                                   // [B][257][256] f32
    float* validf  = protos + (size_t)BB * PPAD * CC;      // [B][257]
    float* masksum = validf + (size_t)BB * PPAD;           // [B]
    unsigned short* Bimg = (unsigned short*)(masksum + BB); // [B][8][2][256][40] halves

    hipLaunchKernelGGL(k0_masks, dim3(BB), dim3(256), 0, stream, msk, bg, validf, masksum);
    hipLaunchKernelGGL(k1_pool, dim3(BB * CC), dim3(256), 0, stream, sup, msk, protos);
    hipLaunchKernelGGL(k2_norm, dim3(BB * PPAD), dim3(256), 0, stream, protos, masksum, Bimg);
    hipLaunchKernelGGL(k3_mfma, dim3(BB * (HWW / 128)), dim3(256), 0, stream,
                       qry, Bimg, protos, validf, out);
}

// Round 4
// 72.503 us; speedup vs baseline: 5.0436x; 1.1107x over previous
//
#include <hip/hip_runtime.h>

#define BB 8
#define CC 256
#define HH 96
#define WW 96
#define HWW (HH*WW)
#define NLOC 256        // local prototypes (MFMA path)
#define PPAD 257        // + global prototype
#define THRESH 0.95f
#define NORM_EPS 1e-4f

typedef __attribute__((ext_vector_type(8))) short bf16x8;
typedef __attribute__((ext_vector_type(4))) float f32x4;

// ---- fused kernel 0+1: mask pooling (8 blocks) + feature pooling (2048) ----
__global__ void k01(const float* __restrict__ sup_fts,
                    const float* __restrict__ sup_mask,
                    const float* __restrict__ true_bg,
                    float* __restrict__ protos,
                    float* __restrict__ validf,
                    float* __restrict__ masksum) {
    __shared__ float red[256];
    int blk = blockIdx.x;
    int t = threadIdx.x;
    if (blk < BB * CC) {
        // ---- k1: avg-pool sup_fts + masked sums (gproto numerator) ----
        int b = blk >> 8, c = blk & 255;
        int gy = t >> 4, gx = t & 15;
        const float* fb = sup_fts + ((size_t)b * CC + c) * HWW;
        const float* mb = sup_mask + (size_t)b * HWW;
        int base = gy * 6 * WW + gx * 6;
        float fs = 0.f, fm = 0.f;
        for (int r = 0; r < 6; ++r) {
            const float* rowf = fb + base + r * WW;
            const float* rowm = mb + base + r * WW;
#pragma unroll
            for (int h = 0; h < 3; ++h) {
                float2 v  = *(const float2*)(rowf + 2 * h);
                float2 mk = *(const float2*)(rowm + 2 * h);
                fs += v.x + v.y;
                fm = fmaf(v.x, mk.x, fm);
                fm = fmaf(v.y, mk.y, fm);
            }
        }
        protos[((size_t)b * PPAD + t) * CC + c] = fs * (1.f / 36.f);
        red[t] = fm;
        __syncthreads();
        for (int off = 128; off > 0; off >>= 1) {
            if (t < off) red[t] += red[t + off];
            __syncthreads();
        }
        if (t == 0) protos[((size_t)b * PPAD + 256) * CC + c] = red[0];
    } else {
        // ---- k0: pooled masks -> valid flags + mask sum ----
        int b = blk - BB * CC;
        int gy = t >> 4, gx = t & 15;
        const float* mb = sup_mask + (size_t)b * HWW;
        const float* gb = true_bg  + (size_t)b * HWW;
        int base = gy * 6 * WW + gx * 6;
        float ms = 0.f, bs = 0.f;
        for (int r = 0; r < 6; ++r) {
            const float* rowm = mb + base + r * WW;
            const float* rowg = gb + base + r * WW;
#pragma unroll
            for (int h = 0; h < 3; ++h) {
                float2 mk = *(const float2*)(rowm + 2 * h);
                float2 bg2 = *(const float2*)(rowg + 2 * h);
                ms += mk.x + mk.y;
                bs += bg2.x + bg2.y;
            }
        }
        float mmean = ms * (1.f / 36.f);
        float bmean = bs * (1.f / 36.f);
        validf[b * PPAD + t] = (mmean > THRESH && bmean < 0.5f) ? 1.f : 0.f;
        if (t == 0) validf[b * PPAD + 256] = 1.f;
        red[t] = ms;
        __syncthreads();
        for (int off = 128; off > 0; off >>= 1) {
            if (t < off) red[t] += red[t + off];
            __syncthreads();
        }
        if (t == 0) masksum[b] = red[0];
    }
}

// ------- kernel 2: finish gproto + normalize + emit bf16 hi/lo B-image ------
// Bimg layout (halves): [B][8 kc][2 ph][2 pl][128 p'][40]   (rows padded 32->40)
__global__ void k2_norm(float* __restrict__ protos,
                        const float* __restrict__ masksum,
                        unsigned short* __restrict__ Bimg) {
    int bp = blockIdx.x;
    int b = bp / PPAD;
    int p = bp - b * PPAD;
    int t = threadIdx.x;            // channel
    float v = protos[((size_t)b * PPAD + p) * CC + t];
    if (p == 256) v = v / (masksum[b] + 1e-5f);
    __shared__ float red[256];
    red[t] = v * v;
    __syncthreads();
    for (int off = 128; off > 0; off >>= 1) {
        if (t < off) red[t] += red[t + off];
        __syncthreads();
    }
    float norm = sqrtf(red[0]);
    float vn = v / fmaxf(norm, NORM_EPS);
    protos[((size_t)b * PPAD + p) * CC + t] = vn;
    if (p < NLOC) {
        unsigned int u = __float_as_uint(vn);
        unsigned short hi = (unsigned short)(u >> 16);          // truncation
        float lo = vn - __uint_as_float(u & 0xffff0000u);       // exact
        unsigned int ul = __float_as_uint(lo);
        unsigned short lob = (unsigned short)((ul + 0x7fffu + ((ul >> 16) & 1u)) >> 16); // RNE
        int kc = t >> 5, j = t & 31;
        int ph = p >> 7, pp = p & 127;
        size_t base = ((((size_t)b * 8 + kc) * 2 + ph) * 2) * (128 * 40);
        Bimg[base + (size_t)pp * 40 + j] = hi;                  // pl=0 (hi)
        Bimg[base + 128 * 40 + (size_t)pp * 40 + j] = lob;      // pl=1 (lo)
    }
}

// ---------------- kernel 3: MFMA dists + masked softmax + weighted sum ------
// block = 256 thr = 4 waves; wave w owns 32 pixels (2 subtiles of 16), N=256.
// 2-phase dbuf pipeline: 16 chunk-iters (8 kc x 2 proto-halves of 128).
#define COMPUTE_PH(PH, BUF)                                                        \
    {                                                                              \
        _Pragma("unroll")                                                          \
        for (int ttl = 0; ttl < 8; ++ttl) {                                        \
            int rowoff = (ttl * 16 + n) * 40 + g * 8;                              \
            bf16x8 bh = *(const bf16x8*)&Blds[BUF][rowoff];                        \
            bf16x8 bl = *(const bf16x8*)&Blds[BUF][5120 + rowoff];                 \
            _Pragma("unroll")                                                      \
            for (int sub = 0; sub < 2; ++sub) {                                    \
                acc[sub][(PH)*8 + ttl] = __builtin_amdgcn_mfma_f32_16x16x32_bf16(  \
                    AH[sub], bh, acc[sub][(PH)*8 + ttl], 0, 0, 0);                 \
                acc[sub][(PH)*8 + ttl] = __builtin_amdgcn_mfma_f32_16x16x32_bf16(  \
                    AL[sub], bh, acc[sub][(PH)*8 + ttl], 0, 0, 0);                 \
                acc[sub][(PH)*8 + ttl] = __builtin_amdgcn_mfma_f32_16x16x32_bf16(  \
                    AH[sub], bl, acc[sub][(PH)*8 + ttl], 0, 0, 0);                 \
            }                                                                      \
        }                                                                          \
    }

__global__ __launch_bounds__(256, 2)
void k3_mfma(const float* __restrict__ qry,
             const unsigned short* __restrict__ Bimg,
             const float* __restrict__ protos_n,
             const float* __restrict__ validf,
             float* __restrict__ out) {
    __shared__ alignas(16) unsigned short Blds[2][10240];   // 2 x 20480 B

    int bid = blockIdx.x;
    int b = bid / (HWW / 128);
    int tile = bid - b * (HWW / 128);
    int t = threadIdx.x;
    int lane = t & 63;
    int w = t >> 6;
    int g = lane >> 4;        // k-group within wave
    int n = lane & 15;        // col lane (proto) / pixel lane for loads
    int px0 = tile * 128 + w * 32;

    const float* qb = qry + (size_t)b * CC * HWW;
    const float* gp = protos_n + ((size_t)b * PPAD + 256) * CC;
    const unsigned short* Bg = Bimg + (size_t)b * 8 * 2 * 2 * (128 * 40);

    f32x4 acc[2][16];
#pragma unroll
    for (int sub = 0; sub < 2; ++sub)
#pragma unroll
        for (int tt = 0; tt < 16; ++tt)
            acc[sub][tt] = (f32x4){0.f, 0.f, 0.f, 0.f};
    float norm2[2] = {0.f, 0.f};
    float gacc[2] = {0.f, 0.f};
    float q2[2][8];
    float gpv[8];
    bf16x8 AH[2], AL[2];

    // ---- stage one 20480B chunk (kc, ph) into LDS buffer ----
    auto STAGE = [&](int kc, int ph, int buf) {
        const char* src = (const char*)(Bg + (size_t)(kc * 2 + ph) * (2 * 128 * 40));
        const char* dst = (const char*)(&Blds[buf][0]) + w * 1024;  // wave-uniform; HW adds lane*16
        int goff = t * 16;
#pragma unroll
        for (int i = 0; i < 5; ++i)
            __builtin_amdgcn_global_load_lds((const void*)(src + i * 4096 + goff),
                                             (void*)(dst + i * 4096), 16, 0, 0);
    };

    auto QLOAD = [&](int kc) {
        int c0 = kc * 32;
#pragma unroll
        for (int sub = 0; sub < 2; ++sub) {
            const float* qcol = qb + (size_t)(c0 + 8 * g) * HWW + (px0 + sub * 16 + n);
#pragma unroll
            for (int j = 0; j < 8; ++j) q2[sub][j] = qcol[(size_t)j * HWW];
        }
#pragma unroll
        for (int j = 0; j < 8; ++j) gpv[j] = gp[c0 + 8 * g + j];
    };

    auto SPLITACC = [&]() {
#pragma unroll
        for (int sub = 0; sub < 2; ++sub) {
            union { bf16x8 v; unsigned int u[4]; } H, L;
#pragma unroll
            for (int jp = 0; jp < 4; ++jp) {
                unsigned int u0 = __float_as_uint(q2[sub][2 * jp]);
                unsigned int u1 = __float_as_uint(q2[sub][2 * jp + 1]);
                H.u[jp] = (u0 >> 16) | (u1 & 0xffff0000u);
                float lo0 = q2[sub][2 * jp]     - __uint_as_float(u0 & 0xffff0000u);
                float lo1 = q2[sub][2 * jp + 1] - __uint_as_float(u1 & 0xffff0000u);
                unsigned int r0 = __float_as_uint(lo0);
                unsigned int r1 = __float_as_uint(lo1);
                r0 = (r0 + 0x7fffu + ((r0 >> 16) & 1u)) >> 16;
                r1 = (r1 + 0x7fffu + ((r1 >> 16) & 1u)) & 0xffff0000u;
                L.u[jp] = r0 | r1;
            }
            AH[sub] = H.v; AL[sub] = L.v;
#pragma unroll
            for (int j = 0; j < 8; ++j) {
                norm2[sub] = fmaf(q2[sub][j], q2[sub][j], norm2[sub]);
                gacc[sub]  = fmaf(q2[sub][j], gpv[j], gacc[sub]);
            }
        }
    };

    // ---- pipelined main loop ----
    STAGE(0, 0, 0);
    QLOAD(0);
    __syncthreads();            // drains stage(0,0) + q(0)
    SPLITACC();                 // kc=0 A-frags
    for (int kc = 0; kc < 8; ++kc) {
        STAGE(kc, 1, 1);                    // next chunk -> buf1
        if (kc < 7) QLOAD(kc + 1);          // prefetch next kc's q
        COMPUTE_PH(0, 0);                   // consume buf0 (protos ph=0)
        __syncthreads();                    // drains stage(kc,1) [+ qloads]
        if (kc < 7) STAGE(kc + 1, 0, 0);    // next kc chunk -> buf0
        COMPUTE_PH(1, 1);                   // consume buf1 (protos ph=1)
        __syncthreads();                    // drains stage(kc+1,0)
        if (kc < 7) SPLITACC();             // split next kc's A (q arrived)
    }

    // ---- reduce |q|^2 and g-dot over k-groups (lanes n, n+16, n+32, n+48) --
#pragma unroll
    for (int sub = 0; sub < 2; ++sub) {
        norm2[sub] += __shfl_xor(norm2[sub], 16);
        norm2[sub] += __shfl_xor(norm2[sub], 32);
        gacc[sub]  += __shfl_xor(gacc[sub], 16);
        gacc[sub]  += __shfl_xor(gacc[sub], 32);
    }

    // per-row (px = px0 + sub*16 + 4g + r) norm & global-proto dist
    float rnorm[2][4], gd[2][4];
#pragma unroll
    for (int sub = 0; sub < 2; ++sub)
#pragma unroll
        for (int r = 0; r < 4; ++r) {
            float n2 = __shfl(norm2[sub], 4 * g + r);
            float rn = 1.f / fmaxf(sqrtf(n2), NORM_EPS);
            rnorm[sub][r] = rn;
            gd[sub][r] = __shfl(gacc[sub], 4 * g + r) * rn;
        }

    // valid flags for this lane's proto column across the 16 tiles
    float vf[16];
    const float* vb = validf + b * PPAD;
#pragma unroll
    for (int tt = 0; tt < 16; ++tt) vf[tt] = vb[tt * 16 + n];

    // ---- softmax (fixed shift 1.1, cosines bounded) + weighted sum ----
    // global-proto term added ONCE per pixel AFTER the 16-lane reduction.
#pragma unroll
    for (int sub = 0; sub < 2; ++sub) {
        float S[4] = {0.f, 0.f, 0.f, 0.f};
        float NN[4] = {0.f, 0.f, 0.f, 0.f};
#pragma unroll
        for (int tt = 0; tt < 16; ++tt) {
#pragma unroll
            for (int r = 0; r < 4; ++r) {
                float d = acc[sub][tt][r] * rnorm[sub][r];
                float l = (vf[tt] != 0.f) ? d : -1e30f;
                float e = __expf(l - 1.1f);          // underflows to exactly 0 when masked
                S[r] += e;
                NN[r] = fmaf(e, l, NN[r]);
            }
        }
#pragma unroll
        for (int r = 0; r < 4; ++r) {
#pragma unroll
            for (int m = 1; m < 16; m <<= 1) {
                S[r]  += __shfl_xor(S[r], m);
                NN[r] += __shfl_xor(NN[r], m);
            }
            float eg = __expf(gd[sub][r] - 1.1f);    // global proto, exactly once
            S[r] += eg;
            NN[r] = fmaf(eg, gd[sub][r], NN[r]);
        }
        if (n < 4) {   // lane (g, n<4) writes row 4g+n, slot r=n
            float Ssel = (n == 0) ? S[0] : (n == 1) ? S[1] : (n == 2) ? S[2] : S[3];
            float Nsel = (n == 0) ? NN[0] : (n == 1) ? NN[1] : (n == 2) ? NN[2] : NN[3];
            out[(size_t)b * HWW + px0 + sub * 16 + 4 * g + n] = Nsel / Ssel;
        }
    }
}

extern "C" void kernel_launch(void* const* d_in, const int* in_sizes, int n_in,
                              void* d_out, int out_size, void* d_ws, size_t ws_size,
                              hipStream_t stream) {
    const float* qry = (const float*)d_in[0];
    const float* sup = (const float*)d_in[1];
    const float* msk = (const float*)d_in[2];
    const float* bg  = (const float*)d_in[3];
    float* out = (float*)d_out;

    float* ws = (float*)d_ws;
    float* protos  = ws;                                   // [B][257][256] f32
    float* validf  = protos + (size_t)BB * PPAD * CC;      // [B][257]
    float* masksum = validf + (size_t)BB * PPAD;           // [B]
    unsigned short* Bimg = (unsigned short*)(masksum + BB); // [B][8][2][2][128][40] halves

    hipLaunchKernelGGL(k01, dim3(BB * CC + BB), dim3(256), 0, stream,
                       sup, msk, bg, protos, validf, masksum);
    hipLaunchKernelGGL(k2_norm, dim3(BB * PPAD), dim3(256), 0, stream, protos, masksum, Bimg);
    hipLaunchKernelGGL(k3_mfma, dim3(BB * (HWW / 128)), dim3(256), 0, stream,
                       qry, Bimg, protos, validf, out);
}